// Round 5
// baseline (145.862 us; speedup 1.0000x reference)
//
#include <hip/hip_runtime.h>
#include <math.h>

// Problem constants
#define B_   64
#define IC_  4096
#define NC_  16
#define D_   16
#define PADF 132   // 128 floats/row + 4 pad
#define CH_  2     // i's per double-buffered W chunk

__device__ inline float dot8(const float4& a0, const float4& a1,
                             const float4& b0, const float4& b1) {
    float r = a0.x * b0.x;
    r = fmaf(a0.y, b0.y, r); r = fmaf(a0.z, b0.z, r); r = fmaf(a0.w, b0.w, r);
    r = fmaf(a1.x, b1.x, r); r = fmaf(a1.y, b1.y, r); r = fmaf(a1.z, b1.z, r);
    r = fmaf(a1.w, b1.w, r);
    return r;
}

// Sum-rotate within 16-lane DPP rows (the j dimension) on the VALU pipe.
// row_ror:N = 0x120|N. After rors 8,4,2,1 every lane holds the full 16-sum.
template <int CTRL>
__device__ inline float ror_add(float v) {
    int r = __builtin_amdgcn_update_dpp(0, __float_as_int(v), CTRL, 0xf, 0xf, false);
    return v + __int_as_float(r);
}

// Pass kernel. Block = 256 thr (4 waves): j = tid&15, c = (tid>>4)&3 (d-quad),
// wv = tid>>6. Wave wv owns 4 batches b0 = bg*16 + wv*4. W double-buffered in
// LDS (coalesced stage); x loaded per-i from global via wave-uniform pointer
// (L1/scalar). Logits collapse to osum . u_hat; softmax over j: 2 shfl_xor
// (c-reduce) + 4 DPP ror-adds. Grid = 4*NI blocks: (bg 0..3) x (NI i-blocks).
__global__ __launch_bounds__(256, 4)
void caps_pass(const float* __restrict__ inp, const float* __restrict__ W,
               const float* __restrict__ osum, float* __restrict__ partials,
               int ipb, int use_osum)
{
    __shared__ float wlds[2][CH_ * NC_ * PADF];  // 33792 B

    const int tid = threadIdx.x;
    const int j   = tid & 15;
    const int c   = (tid >> 4) & 3;
    const int wv  = tid >> 6;

    // XCD-aware swizzle; consecutive wg share i-range (4 bg's adjacent).
    const int n   = blockIdx.x;
    const int cpx = gridDim.x >> 3;
    const int wg  = (n & 7) * cpx + (n >> 3);
    const int ib  = wg >> 2;
    const int bg  = wg & 3;
    const int i0  = ib * ipb;
    const int b0  = bg * 16 + wv * 4;
    const int b0u = __builtin_amdgcn_readfirstlane(b0);  // wave-uniform batch base

    // ---- W staging: thread t covers float4 rows r0 and r0+8, col k ----
    const int r0 = tid >> 5;   // 0..7
    const int k  = tid & 31;   // 0..31
    const float4* Wf4 = (const float4*)W;

    float4 p00, p01, p10, p11;
    // prologue: chunk 0 (i0, i0+1)
    p00 = Wf4[((size_t)r0 * IC_ + i0) * 32 + k];
    p01 = Wf4[((size_t)(r0 + 8) * IC_ + i0) * 32 + k];
    p10 = Wf4[((size_t)r0 * IC_ + i0 + 1) * 32 + k];
    p11 = Wf4[((size_t)(r0 + 8) * IC_ + i0 + 1) * 32 + k];
    *(float4*)&wlds[0][(r0) * PADF + k * 4]            = p00;
    *(float4*)&wlds[0][(r0 + 8) * PADF + k * 4]        = p01;
    *(float4*)&wlds[0][(NC_ + r0) * PADF + k * 4]      = p10;
    *(float4*)&wlds[0][(NC_ + r0 + 8) * PADF + k * 4]  = p11;
    __syncthreads();

    // osum rows for my 4 batches (registers)
    float4 os[4];
    if (use_osum) {
#pragma unroll
        for (int bi = 0; bi < 4; ++bi)
            os[bi] = ((const float4*)osum)[((size_t)(b0 + bi) * 16 + j) * 4 + c];
    }

    float acc[4][4];
#pragma unroll
    for (int bi = 0; bi < 4; ++bi)
#pragma unroll
        for (int dl = 0; dl < 4; ++dl) acc[bi][dl] = 0.0f;

    const int nch = ipb >> 1;
    int cur = 0;
    for (int ch = 0; ch < nch; ++ch) {
        const int ibase = i0 + ch * 2;
        if (ch + 1 < nch) {  // prefetch next chunk (global -> regs)
            p00 = Wf4[((size_t)r0 * IC_ + ibase + 2) * 32 + k];
            p01 = Wf4[((size_t)(r0 + 8) * IC_ + ibase + 2) * 32 + k];
            p10 = Wf4[((size_t)r0 * IC_ + ibase + 3) * 32 + k];
            p11 = Wf4[((size_t)(r0 + 8) * IC_ + ibase + 3) * 32 + k];
        }
#pragma unroll
        for (int il = 0; il < CH_; ++il) {
            const int i = ibase + il;
            const float* row = &wlds[cur][(il * NC_ + j) * PADF + c * 32];
            float4 w0 = *(const float4*)&row[0],  w1 = *(const float4*)&row[4];
            float4 w2 = *(const float4*)&row[8],  w3 = *(const float4*)&row[12];
            float4 w4 = *(const float4*)&row[16], w5 = *(const float4*)&row[20];
            float4 w6 = *(const float4*)&row[24], w7 = *(const float4*)&row[28];

            float uh[4][4];
#pragma unroll
            for (int bi = 0; bi < 4; ++bi) {
                // wave-uniform address -> scalar/L1 load, no LDS
                const float4* xp =
                    (const float4*)(inp + ((size_t)(b0u + bi) * IC_ + i) * 8);
                float4 xa = xp[0];
                float4 xb = xp[1];
                uh[bi][0] = dot8(w0, w1, xa, xb);
                uh[bi][1] = dot8(w2, w3, xa, xb);
                uh[bi][2] = dot8(w4, w5, xa, xb);
                uh[bi][3] = dot8(w6, w7, xa, xb);
            }

            float cc[4];
            if (use_osum) {
                float pb[4];
#pragma unroll
                for (int bi = 0; bi < 4; ++bi) {
                    float r = os[bi].x * uh[bi][0];
                    r = fmaf(os[bi].y, uh[bi][1], r);
                    r = fmaf(os[bi].z, uh[bi][2], r);
                    r = fmaf(os[bi].w, uh[bi][3], r);
                    pb[bi] = r;
                }
#pragma unroll
                for (int bi = 0; bi < 4; ++bi) {  // reduce over d-quads (c bits)
                    pb[bi] += __shfl_xor(pb[bi], 16);
                    pb[bi] += __shfl_xor(pb[bi], 32);
                }
#pragma unroll
                for (int bi = 0; bi < 4; ++bi) {
                    float e  = __expf(pb[bi]);          // no max-sub: |logit| small
                    float sm = ror_add<0x128>(e);       // sum over j via DPP rors
                    sm = ror_add<0x124>(sm);
                    sm = ror_add<0x122>(sm);
                    sm = ror_add<0x121>(sm);
                    cc[bi] = __fdividef(e, sm);
                }
            } else {
#pragma unroll
                for (int bi = 0; bi < 4; ++bi) cc[bi] = 0.0625f;
            }

#pragma unroll
            for (int bi = 0; bi < 4; ++bi)
#pragma unroll
                for (int dl = 0; dl < 4; ++dl)
                    acc[bi][dl] = fmaf(cc[bi], uh[bi][dl], acc[bi][dl]);
        }
        if (ch + 1 < nch) {  // write prefetched chunk to other buffer
            const int nb = cur ^ 1;
            *(float4*)&wlds[nb][(r0) * PADF + k * 4]           = p00;
            *(float4*)&wlds[nb][(r0 + 8) * PADF + k * 4]       = p01;
            *(float4*)&wlds[nb][(NC_ + r0) * PADF + k * 4]     = p10;
            *(float4*)&wlds[nb][(NC_ + r0 + 8) * PADF + k * 4] = p11;
        }
        __syncthreads();
        cur ^= 1;
    }

    // partials[ib][b][j][d], coalesced float4 stores
#pragma unroll
    for (int bi = 0; bi < 4; ++bi)
        ((float4*)partials)[(((size_t)ib * B_ + b0 + bi) * NC_ + j) * 4 + c] =
            make_float4(acc[bi][0], acc[bi][1], acc[bi][2], acc[bi][3]);
}

// Reduce over NI i-blocks + squash. Grid = 1024 blocks (one per (b,j) pair),
// 256 thr = 64 ksplit x 4 d-quads, float4 loads throughout.
// mode 0: osum = out ; mode 1: osum += out ; mode 2: d_out = out
__global__ __launch_bounds__(256)
void caps_reduce(const float* __restrict__ partials, float* __restrict__ osum,
                 float* __restrict__ outb, int NI, int mode)
{
    __shared__ float4 red[256];
    const int tid = threadIdx.x;
    const int o4  = tid & 3;
    const int ks  = tid >> 2;
    const int bj  = blockIdx.x;
    const float4* p4 = (const float4*)partials;

    float4 s = make_float4(0.f, 0.f, 0.f, 0.f);
    for (int ibk = ks; ibk < NI; ibk += 64) {
        float4 v = p4[(size_t)ibk * (B_ * NC_ * 4) + bj * 4 + o4];
        s.x += v.x; s.y += v.y; s.z += v.z; s.w += v.w;
    }
    red[tid] = s;
    __syncthreads();
    if (tid < 64) {
        float4 a = red[tid], b = red[tid + 64], c = red[tid + 128], d = red[tid + 192];
        s.x = a.x + b.x + c.x + d.x; s.y = a.y + b.y + c.y + d.y;
        s.z = a.z + b.z + c.z + d.z; s.w = a.w + b.w + c.w + d.w;
        red[tid] = s;
    }
    __syncthreads();
    if (tid < 4) {
        float4 t = red[tid];
#pragma unroll
        for (int kk = 1; kk < 16; ++kk) {
            float4 v = red[kk * 4 + tid];
            t.x += v.x; t.y += v.y; t.z += v.z; t.w += v.w;
        }
        float s2 = t.x * t.x + t.y * t.y + t.z * t.z + t.w * t.w;
        s2 += __shfl_xor(s2, 1);
        s2 += __shfl_xor(s2, 2);
        float scale = s2 / (1.0f + s2) * rsqrtf(s2 + 1e-7f);
        float4 o = make_float4(scale * t.x, scale * t.y, scale * t.z, scale * t.w);
        size_t fi = (size_t)bj * 4 + tid;
        if (mode == 0) ((float4*)osum)[fi] = o;
        else if (mode == 1) {
            float4 cu = ((float4*)osum)[fi];
            cu.x += o.x; cu.y += o.y; cu.z += o.z; cu.w += o.w;
            ((float4*)osum)[fi] = cu;
        } else ((float4*)outb)[fi] = o;
    }
}

extern "C" void kernel_launch(void* const* d_in, const int* in_sizes, int n_in,
                              void* d_out, int out_size, void* d_ws, size_t ws_size,
                              hipStream_t stream)
{
    const float* inp = (const float*)d_in[0];  // [64, 4096, 8]
    const float* W   = (const float*)d_in[1];  // [16, 4096, 16, 8]
    float* out  = (float*)d_out;               // [64, 16, 16]

    float* osum     = (float*)d_ws;                   // 16 KB used
    float* partials = (float*)((char*)d_ws + 65536);  // NI * 64 KB

    long cap = (long)(ws_size / 65536) - 1;  // NI units of 64 KB
    const int NI  = (cap >= 256) ? 256 : 128;
    const int ipb = IC_ / NI;                // 16 (or 32 fallback)
    dim3 grid(4 * NI);

    // iter 0: c uniform (softmax of zeros)
    caps_pass<<<grid, 256, 0, stream>>>(inp, W, osum, partials, ipb, 0);
    caps_reduce<<<1024, 256, 0, stream>>>(partials, osum, out, NI, 0);
    // iter 1: logits = out0 . u_hat
    caps_pass<<<grid, 256, 0, stream>>>(inp, W, osum, partials, ipb, 1);
    caps_reduce<<<1024, 256, 0, stream>>>(partials, osum, out, NI, 1);
    // iter 2: logits = (out0 + out1) . u_hat
    caps_pass<<<grid, 256, 0, stream>>>(inp, W, osum, partials, ipb, 1);
    caps_reduce<<<1024, 256, 0, stream>>>(partials, osum, out, NI, 2);
}